// Round 9
// baseline (474.884 us; speedup 1.0000x reference)
//
#include <hip/hip_runtime.h>
#include <hip/hip_bf16.h>
#include <math.h>

typedef __attribute__((ext_vector_type(8))) short  short8;
typedef __attribute__((ext_vector_type(4))) float  f32x4;
typedef __attribute__((ext_vector_type(4))) unsigned short u16x4;
typedef __attribute__((ext_vector_type(8))) unsigned short u16x8;

#define BATCH 16384
#define NF    64
#define BAGL  10
#define ED    16
#define DW    1024   // F*E
#define VOCAB 1000000

static __device__ __forceinline__ unsigned short f2bf(float f) {
    unsigned int u = __builtin_bit_cast(unsigned int, f);
    unsigned int r = (u + 0x7fffu + ((u >> 16) & 1u)) >> 16;
    return (unsigned short)r;
}
static __device__ __forceinline__ float bf2f(unsigned short h) {
    unsigned int u = ((unsigned int)h) << 16;
    return __builtin_bit_cast(float, u);
}

// ---------------- 1. embedding gather + bag-sum (f32 table), bf16 x --------
// 4 threads/bag, 16B each; 16384 short blocks = max occupancy (r8 showed pool
// rate scales with resident waves; serial batching/deeper MLP both falsified).
__global__ __launch_bounds__(256) void pool_kernel(const int* __restrict__ idx,
                                                   const float* __restrict__ emb,
                                                   unsigned short* __restrict__ xb) {
    const int gid = blockIdx.x * 256 + threadIdx.x;   // B*F*4 threads
    const int bag = gid >> 2;                         // b*F + f
    const int q   = gid & 3;                          // which float4 of E=16
    const int* ip = idx + (long long)bag * BAGL;

    int v[BAGL];
#pragma unroll
    for (int l = 0; l < BAGL; ++l) v[l] = ip[l];
    f32x4 e[BAGL];
#pragma unroll
    for (int l = 0; l < BAGL; ++l)
        e[l] = *(const f32x4*)(emb + (((long long)v[l]) << 4) + (q << 2));

    f32x4 s01 = e[0] + e[1], s23 = e[2] + e[3], s45 = e[4] + e[5],
          s67 = e[6] + e[7], s89 = e[8] + e[9];
    f32x4 acc = ((s01 + s23) + (s45 + s67)) + s89;

    u16x4 o;
#pragma unroll
    for (int j = 0; j < 4; ++j) o[j] = f2bf(acc[j]);
    *(u16x4*)(xb + (((long long)bag) << 4) + (q << 2)) = o;
}

// ---------------- 2. per-column sum / sumsq over batch ---------------------
__global__ __launch_bounds__(256) void stats_kernel(const unsigned short* __restrict__ xb,
                                                    float* __restrict__ ssum,
                                                    float* __restrict__ ssq) {
    const int t = threadIdx.x;                 // cols 4t..4t+3
    const long long r0 = (long long)blockIdx.x * 8;
    float s[4] = {0, 0, 0, 0}, q[4] = {0, 0, 0, 0};
    for (int r = 0; r < 8; ++r) {
        const u16x4 v = *(const u16x4*)(xb + (r0 + r) * DW + t * 4);
#pragma unroll
        for (int j = 0; j < 4; ++j) { float f = bf2f(v[j]); s[j] += f; q[j] += f * f; }
    }
#pragma unroll
    for (int j = 0; j < 4; ++j) {
        atomicAdd(&ssum[t * 4 + j], s[j]);
        atomicAdd(&ssq [t * 4 + j], q[j]);
    }
}

static __device__ __forceinline__ float rsig_of(const float* ssum, const float* ssq, int c) {
    const float m = ssum[c] * (1.0f / (float)BATCH);
    const float v = ssq[c] * (1.0f / (float)BATCH) - m * m;
    return rsqrtf(v + 1e-5f);
}

// ---------------- 3. weight prep, one launch -------------------------------
// z=0: w1t[c][r] = W1[r][c]*rsig[r]; z=1: w2t[c][r] = W2[r][c];
// z=2 (bx<4, by<8): b1n[n] -= sum_k mu[k]*rsig[k]*W1[k,n]
__global__ __launch_bounds__(256) void prep_weights(const float* __restrict__ W1,
                                                    const float* __restrict__ W2,
                                                    const float* __restrict__ ssum,
                                                    const float* __restrict__ ssq,
                                                    unsigned short* __restrict__ w1t,
                                                    unsigned short* __restrict__ w2t,
                                                    float* __restrict__ b1n) {
    const int z = blockIdx.z;
    const int bx = blockIdx.x, by = blockIdx.y;
    if (z == 2) {
        if (bx >= 4 || by >= 8) return;
        __shared__ float mu_s[128];
        const int n = bx * 256 + threadIdx.x;
        const int k0 = by * 128;
        if (threadIdx.x < 128) {
            const int k = k0 + threadIdx.x;
            mu_s[threadIdx.x] = ssum[k] * (1.0f / (float)BATCH) * rsig_of(ssum, ssq, k);
        }
        __syncthreads();
        float acc = 0.f;
#pragma unroll 4
        for (int k = 0; k < 128; ++k)
            acc += mu_s[k] * W1[(long long)(k0 + k) * 1024 + n];
        atomicAdd(&b1n[n], -acc);
        return;
    }
    if (z == 1 && bx >= 16) return;
    __shared__ float tile[32][33];
    const int tx = threadIdx.x & 31, ty = threadIdx.x >> 5;
    const float* src = z ? W2 : W1;
    unsigned short* dst = z ? w2t : w1t;
    const int C = z ? 512 : 1024;
#pragma unroll
    for (int i = 0; i < 4; ++i) {
        const int r = by * 32 + ty + i * 8, c = bx * 32 + tx;
        float v = src[(long long)r * C + c];
        if (!z) v *= rsig_of(ssum, ssq, r);
        tile[ty + i * 8][tx] = v;
    }
    __syncthreads();
#pragma unroll
    for (int i = 0; i < 4; ++i) {
        const int oc = bx * 32 + ty + i * 8;
        dst[(long long)oc * 1024 + by * 32 + tx] = f2bf(tile[tx][ty + i * 8]);
    }
}

// ============ pipelined 128x128 bf16 GEMM core (proven r5 structure) =======
#define GEMM_STAGE(dstA, dstB, kt)                                              \
  {                                                                             \
    const int k0s = (kt) * 64;                                                  \
    _Pragma("unroll")                                                           \
    for (int g = 0; g < 4; ++g) {                                               \
      const int cid = g * 256 + tid;                                            \
      const int rr = cid >> 3, pos = cid & 7;                                   \
      const int csrc = (pos ^ (rr & 7)) << 3;                                   \
      __builtin_amdgcn_global_load_lds(                                         \
        (const __attribute__((address_space(1))) void*)(A + a_base + (long long)rr * K + k0s + csrc), \
        (__attribute__((address_space(3))) void*)(&(dstA)[cid * 8]), 16, 0, 0); \
      __builtin_amdgcn_global_load_lds(                                         \
        (const __attribute__((address_space(1))) void*)(Bt + b_base + (long long)rr * K + k0s + csrc), \
        (__attribute__((address_space(3))) void*)(&(dstB)[cid * 8]), 16, 0, 0); \
    }                                                                           \
  }

#define GEMM_CORE_LOOP                                                          \
    const int tid = threadIdx.x;                                                \
    const int w = tid >> 6, l = tid & 63;                                       \
    const int wr = w >> 1, wc = w & 1;                                          \
    const int l15 = l & 15, l4 = l >> 4;                                        \
    f32x4 acc[4][4] = {};                                                       \
    const long long a_base = (long long)bm * 128 * K;                           \
    const long long b_base = (long long)bn * 128 * K;                           \
    const int NT = K >> 6;                                                      \
    GEMM_STAGE(As[0], Bs[0], 0)                                                 \
    GEMM_STAGE(As[1], Bs[1], 1)                                                 \
    asm volatile("s_waitcnt vmcnt(8)" ::: "memory");                            \
    __builtin_amdgcn_sched_barrier(0);                                          \
    __builtin_amdgcn_s_barrier();                                               \
    for (int t = 0; t < NT; ++t) {                                              \
        const unsigned short* Ap = As[t & 1];                                   \
        const unsigned short* Bp = Bs[t & 1];                                   \
        short8 a[2][4], b[2][4];                                                \
        _Pragma("unroll")                                                       \
        for (int kk = 0; kk < 2; ++kk) {                                        \
            const int swz = ((kk * 4 + l4) ^ (l15 & 7)) << 3;                   \
            _Pragma("unroll")                                                   \
            for (int m = 0; m < 4; ++m)                                         \
                a[kk][m] = *(const short8*)(Ap + (wr * 64 + m * 16 + l15) * 64 + swz); \
            _Pragma("unroll")                                                   \
            for (int n = 0; n < 4; ++n)                                         \
                b[kk][n] = *(const short8*)(Bp + (wc * 64 + n * 16 + l15) * 64 + swz); \
        }                                                                       \
        asm volatile("s_waitcnt lgkmcnt(0)" ::: "memory");                      \
        __builtin_amdgcn_sched_barrier(0);                                      \
        __builtin_amdgcn_s_barrier();                                           \
        if (t + 2 < NT) { GEMM_STAGE(As[t & 1], Bs[t & 1], t + 2) }             \
        __builtin_amdgcn_s_setprio(1);                                          \
        _Pragma("unroll")                                                       \
        for (int kk = 0; kk < 2; ++kk)                                          \
            _Pragma("unroll")                                                   \
            for (int m = 0; m < 4; ++m)                                         \
                _Pragma("unroll")                                               \
                for (int n = 0; n < 4; ++n)                                     \
                    acc[m][n] = __builtin_amdgcn_mfma_f32_16x16x32_bf16(        \
                        a[kk][m], b[kk][n], acc[kk ? m : m][n], 0, 0, 0);       \
        __builtin_amdgcn_s_setprio(0);                                          \
        if (t + 1 < NT) {                                                       \
            if (t + 2 < NT) { asm volatile("s_waitcnt vmcnt(8)" ::: "memory"); }\
            else            { asm volatile("s_waitcnt vmcnt(0)" ::: "memory"); }\
            __builtin_amdgcn_sched_barrier(0);                                  \
            __builtin_amdgcn_s_barrier();                                       \
        }                                                                       \
    }

// ---------------- 5. GEMM1: C = relu(A@Bt^T + bias + bias2), bf16 ----------
__global__ __launch_bounds__(256, 2) void gemm_relu(const unsigned short* __restrict__ A,
                                                    const unsigned short* __restrict__ Bt,
                                                    const float* __restrict__ bias,
                                                    const float* __restrict__ bias2,
                                                    unsigned short* __restrict__ C,
                                                    int M, int N, int K, int NBN) {
    __shared__ __align__(16) unsigned short As[2][128 * 64];
    __shared__ __align__(16) unsigned short Bs[2][128 * 64];
    const int blk = blockIdx.x, xcd = blk & 7, j = blk >> 3;
    const int bm = xcd * 16 + j / NBN, bn = j % NBN;

    GEMM_CORE_LOOP

#pragma unroll
    for (int m = 0; m < 4; ++m) {
        const int grow_base = bm * 128 + wr * 64 + m * 16 + l4 * 4;
#pragma unroll
        for (int n = 0; n < 4; ++n) {
            const int gcol = bn * 128 + wc * 64 + n * 16 + l15;
            const float bv = bias[gcol] + bias2[gcol];
#pragma unroll
            for (int j2 = 0; j2 < 4; ++j2) {
                float v = fmaxf(acc[m][n][j2] + bv, 0.f);
                C[(long long)(grow_base + j2) * N + gcol] = f2bf(v);
            }
        }
    }
}

// ---------------- 5b. GEMM2 with fused W3-dot epilogue ---------------------
__global__ __launch_bounds__(256, 2) void gemm2_fused(const unsigned short* __restrict__ A,
                                                      const unsigned short* __restrict__ Bt,
                                                      const float* __restrict__ bias,
                                                      const float* __restrict__ W3,
                                                      float* __restrict__ logits,
                                                      int M, int N, int K, int NBN) {
    __shared__ __align__(16) unsigned short As[2][128 * 64];
    __shared__ __align__(16) unsigned short Bs[2][128 * 64];
    const int blk = blockIdx.x, xcd = blk & 7, j = blk >> 3;
    const int bm = xcd * 16 + j / NBN, bn = j % NBN;

    GEMM_CORE_LOOP

#pragma unroll
    for (int m = 0; m < 4; ++m) {
        float part[4] = {0.f, 0.f, 0.f, 0.f};
#pragma unroll
        for (int n = 0; n < 4; ++n) {
            const int gcol = bn * 128 + wc * 64 + n * 16 + l15;
            const float bv = bias[gcol];
            const float w3 = W3[gcol];
#pragma unroll
            for (int j2 = 0; j2 < 4; ++j2) {
                float v = fmaxf(acc[m][n][j2] + bv, 0.f);
                part[j2] += v * w3;
            }
        }
#pragma unroll
        for (int off = 1; off < 16; off <<= 1)
#pragma unroll
            for (int j2 = 0; j2 < 4; ++j2) part[j2] += __shfl_xor(part[j2], off, 64);
        if (l15 == 0) {
            const int grow = bm * 128 + wr * 64 + m * 16 + l4 * 4;
#pragma unroll
            for (int j2 = 0; j2 < 4; ++j2) atomicAdd(&logits[grow + j2], part[j2]);
        }
    }
}

// ---------------- 6. sigmoid ------------------------------------------------
__global__ __launch_bounds__(256) void sigmoid_kernel(const float* __restrict__ logits,
                                                      const float* __restrict__ b3,
                                                      float* __restrict__ out) {
    const int i = blockIdx.x * 256 + threadIdx.x;
    out[i] = 1.0f / (1.0f + expf(-(logits[i] + b3[0])));
}

// ---------------- host ------------------------------------------------------
extern "C" void kernel_launch(void* const* d_in, const int* in_sizes, int n_in,
                              void* d_out, int out_size, void* d_ws, size_t ws_size,
                              hipStream_t stream) {
    const int*   idx = (const int*)d_in[0];
    const float* emb = (const float*)d_in[1];
    const float* W1  = (const float*)d_in[2];
    const float* b1  = (const float*)d_in[3];
    const float* W2  = (const float*)d_in[4];
    const float* b2  = (const float*)d_in[5];
    const float* W3  = (const float*)d_in[6];
    const float* b3  = (const float*)d_in[7];
    float* out = (float*)d_out;

    char* ws = (char*)d_ws;
    unsigned short* xb   = (unsigned short*)ws; ws += (size_t)BATCH * DW * 2;   // 32MB
    unsigned short* h1   = (unsigned short*)ws; ws += (size_t)BATCH * DW * 2;   // 32MB
    unsigned short* w1t  = (unsigned short*)ws; ws += (size_t)1024 * 1024 * 2;  // 2MB
    unsigned short* w2t  = (unsigned short*)ws; ws += (size_t)512 * 1024 * 2;   // 1MB
    float* ssum   = (float*)ws; ws += 4096;
    float* ssq    = (float*)ws; ws += 4096;
    float* b1n    = (float*)ws; ws += 4096;
    float* logits = (float*)ws; ws += (size_t)BATCH * 4;

    hipMemsetAsync(ssum, 0, 4096 * 3 + (size_t)BATCH * 4, stream);

    pool_kernel<<<(BATCH * NF * 4) / 256, 256, 0, stream>>>(idx, emb, xb);
    stats_kernel<<<BATCH / 8, 256, 0, stream>>>(xb, ssum, ssq);

    prep_weights<<<dim3(32, 32, 3), 256, 0, stream>>>(W1, W2, ssum, ssq, w1t, w2t, b1n);

    gemm_relu<<<(BATCH / 128) * (1024 / 128), 256, 0, stream>>>(
        xb, w1t, b1, b1n, h1, BATCH, 1024, 1024, 1024 / 128);
    gemm2_fused<<<(BATCH / 128) * (512 / 128), 256, 0, stream>>>(
        h1, w2t, b2, W3, logits, BATCH, 512, 1024, 512 / 128);

    sigmoid_kernel<<<BATCH / 256, 256, 0, stream>>>(logits, b3, out);
}

// Round 10
// 296.717 us; speedup vs baseline: 1.6005x; 1.6005x over previous
//
#include <hip/hip_runtime.h>
#include <hip/hip_bf16.h>
#include <math.h>

typedef __attribute__((ext_vector_type(8))) short  short8;
typedef __attribute__((ext_vector_type(4))) float  f32x4;
typedef __attribute__((ext_vector_type(4))) unsigned short u16x4;
typedef __attribute__((ext_vector_type(8))) unsigned short u16x8;

#define BATCH 16384
#define NF    64
#define BAGL  10
#define ED    16
#define DW    1024   // F*E
#define VOCAB 1000000

static __device__ __forceinline__ unsigned short f2bf(float f) {
    unsigned int u = __builtin_bit_cast(unsigned int, f);
    unsigned int r = (u + 0x7fffu + ((u >> 16) & 1u)) >> 16;
    return (unsigned short)r;
}
static __device__ __forceinline__ float bf2f(unsigned short h) {
    unsigned int u = ((unsigned int)h) << 16;
    return __builtin_bit_cast(float, u);
}

// ---------------- 1. embedding gather + bag-sum (f32 table), bf16 x --------
// 4 threads/bag, 16B each; 16384 short blocks = max occupancy (pool rate
// scales with resident waves — r8; deeper MLP / serial batching falsified).
__global__ __launch_bounds__(256) void pool_kernel(const int* __restrict__ idx,
                                                   const float* __restrict__ emb,
                                                   unsigned short* __restrict__ xb) {
    const int gid = blockIdx.x * 256 + threadIdx.x;   // B*F*4 threads
    const int bag = gid >> 2;                         // b*F + f
    const int q   = gid & 3;                          // which float4 of E=16
    const int* ip = idx + (long long)bag * BAGL;

    int v[BAGL];
#pragma unroll
    for (int l = 0; l < BAGL; ++l) v[l] = ip[l];
    f32x4 e[BAGL];
#pragma unroll
    for (int l = 0; l < BAGL; ++l)
        e[l] = *(const f32x4*)(emb + (((long long)v[l]) << 4) + (q << 2));

    f32x4 s01 = e[0] + e[1], s23 = e[2] + e[3], s45 = e[4] + e[5],
          s67 = e[6] + e[7], s89 = e[8] + e[9];
    f32x4 acc = ((s01 + s23) + (s45 + s67)) + s89;

    u16x4 o;
#pragma unroll
    for (int j = 0; j < 4; ++j) o[j] = f2bf(acc[j]);
    *(u16x4*)(xb + (((long long)bag) << 4) + (q << 2)) = o;
}

// ---------------- 2. per-column sum / sumsq over batch ---------------------
// 128 blocks x 128-row register accumulation -> 262K atomics (~2K per 64B
// line). r9 lesson: atomic count scales with block count; 2048 blocks put
// 32K serialized ops on each TCC line (202us). Keep blocks low here.
__global__ __launch_bounds__(256) void stats_kernel(const unsigned short* __restrict__ xb,
                                                    float* __restrict__ ssum,
                                                    float* __restrict__ ssq) {
    const int t = threadIdx.x;                 // cols 4t..4t+3
    const long long r0 = (long long)blockIdx.x * 128;
    float s[4] = {0, 0, 0, 0}, q[4] = {0, 0, 0, 0};
    for (int r = 0; r < 128; ++r) {
        const u16x4 v = *(const u16x4*)(xb + (r0 + r) * DW + t * 4);
#pragma unroll
        for (int j = 0; j < 4; ++j) { float f = bf2f(v[j]); s[j] += f; q[j] += f * f; }
    }
#pragma unroll
    for (int j = 0; j < 4; ++j) {
        atomicAdd(&ssum[t * 4 + j], s[j]);
        atomicAdd(&ssq [t * 4 + j], q[j]);
    }
}

static __device__ __forceinline__ float rsig_of(const float* ssum, const float* ssq, int c) {
    const float m = ssum[c] * (1.0f / (float)BATCH);
    const float v = ssq[c] * (1.0f / (float)BATCH) - m * m;
    return rsqrtf(v + 1e-5f);
}

// ---------------- 3. weight prep, one launch -------------------------------
// z=0: w1t[c][r] = W1[r][c]*rsig[r]; z=1: w2t[c][r] = W2[r][c];
// z=2 (bx<4, by<8): b1n[n] -= sum_k mu[k]*rsig[k]*W1[k,n]
__global__ __launch_bounds__(256) void prep_weights(const float* __restrict__ W1,
                                                    const float* __restrict__ W2,
                                                    const float* __restrict__ ssum,
                                                    const float* __restrict__ ssq,
                                                    unsigned short* __restrict__ w1t,
                                                    unsigned short* __restrict__ w2t,
                                                    float* __restrict__ b1n) {
    const int z = blockIdx.z;
    const int bx = blockIdx.x, by = blockIdx.y;
    if (z == 2) {
        if (bx >= 4 || by >= 8) return;
        __shared__ float mu_s[128];
        const int n = bx * 256 + threadIdx.x;
        const int k0 = by * 128;
        if (threadIdx.x < 128) {
            const int k = k0 + threadIdx.x;
            mu_s[threadIdx.x] = ssum[k] * (1.0f / (float)BATCH) * rsig_of(ssum, ssq, k);
        }
        __syncthreads();
        float acc = 0.f;
#pragma unroll 4
        for (int k = 0; k < 128; ++k)
            acc += mu_s[k] * W1[(long long)(k0 + k) * 1024 + n];
        atomicAdd(&b1n[n], -acc);
        return;
    }
    if (z == 1 && bx >= 16) return;
    __shared__ float tile[32][33];
    const int tx = threadIdx.x & 31, ty = threadIdx.x >> 5;
    const float* src = z ? W2 : W1;
    unsigned short* dst = z ? w2t : w1t;
    const int C = z ? 512 : 1024;
#pragma unroll
    for (int i = 0; i < 4; ++i) {
        const int r = by * 32 + ty + i * 8, c = bx * 32 + tx;
        float v = src[(long long)r * C + c];
        if (!z) v *= rsig_of(ssum, ssq, r);
        tile[ty + i * 8][tx] = v;
    }
    __syncthreads();
#pragma unroll
    for (int i = 0; i < 4; ++i) {
        const int oc = bx * 32 + ty + i * 8;
        dst[(long long)oc * 1024 + by * 32 + tx] = f2bf(tile[tx][ty + i * 8]);
    }
}

// ============ pipelined 128x128 bf16 GEMM core (proven r5 structure) =======
#define GEMM_STAGE(dstA, dstB, kt)                                              \
  {                                                                             \
    const int k0s = (kt) * 64;                                                  \
    _Pragma("unroll")                                                           \
    for (int g = 0; g < 4; ++g) {                                               \
      const int cid = g * 256 + tid;                                            \
      const int rr = cid >> 3, pos = cid & 7;                                   \
      const int csrc = (pos ^ (rr & 7)) << 3;                                   \
      __builtin_amdgcn_global_load_lds(                                         \
        (const __attribute__((address_space(1))) void*)(A + a_base + (long long)rr * K + k0s + csrc), \
        (__attribute__((address_space(3))) void*)(&(dstA)[cid * 8]), 16, 0, 0); \
      __builtin_amdgcn_global_load_lds(                                         \
        (const __attribute__((address_space(1))) void*)(Bt + b_base + (long long)rr * K + k0s + csrc), \
        (__attribute__((address_space(3))) void*)(&(dstB)[cid * 8]), 16, 0, 0); \
    }                                                                           \
  }

#define GEMM_CORE_LOOP                                                          \
    const int tid = threadIdx.x;                                                \
    const int w = tid >> 6, l = tid & 63;                                       \
    const int wr = w >> 1, wc = w & 1;                                          \
    const int l15 = l & 15, l4 = l >> 4;                                        \
    f32x4 acc[4][4] = {};                                                       \
    const long long a_base = (long long)bm * 128 * K;                           \
    const long long b_base = (long long)bn * 128 * K;                           \
    const int NT = K >> 6;                                                      \
    GEMM_STAGE(As[0], Bs[0], 0)                                                 \
    GEMM_STAGE(As[1], Bs[1], 1)                                                 \
    asm volatile("s_waitcnt vmcnt(8)" ::: "memory");                            \
    __builtin_amdgcn_sched_barrier(0);                                          \
    __builtin_amdgcn_s_barrier();                                               \
    for (int t = 0; t < NT; ++t) {                                              \
        const unsigned short* Ap = As[t & 1];                                   \
        const unsigned short* Bp = Bs[t & 1];                                   \
        short8 a[2][4], b[2][4];                                                \
        _Pragma("unroll")                                                       \
        for (int kk = 0; kk < 2; ++kk) {                                        \
            const int swz = ((kk * 4 + l4) ^ (l15 & 7)) << 3;                   \
            _Pragma("unroll")                                                   \
            for (int m = 0; m < 4; ++m)                                         \
                a[kk][m] = *(const short8*)(Ap + (wr * 64 + m * 16 + l15) * 64 + swz); \
            _Pragma("unroll")                                                   \
            for (int n = 0; n < 4; ++n)                                         \
                b[kk][n] = *(const short8*)(Bp + (wc * 64 + n * 16 + l15) * 64 + swz); \
        }                                                                       \
        asm volatile("s_waitcnt lgkmcnt(0)" ::: "memory");                      \
        __builtin_amdgcn_sched_barrier(0);                                      \
        __builtin_amdgcn_s_barrier();                                           \
        if (t + 2 < NT) { GEMM_STAGE(As[t & 1], Bs[t & 1], t + 2) }             \
        __builtin_amdgcn_s_setprio(1);                                          \
        _Pragma("unroll")                                                       \
        for (int kk = 0; kk < 2; ++kk)                                          \
            _Pragma("unroll")                                                   \
            for (int m = 0; m < 4; ++m)                                         \
                _Pragma("unroll")                                               \
                for (int n = 0; n < 4; ++n)                                     \
                    acc[m][n] = __builtin_amdgcn_mfma_f32_16x16x32_bf16(        \
                        a[kk][m], b[kk][n], acc[m][n], 0, 0, 0);                \
        __builtin_amdgcn_s_setprio(0);                                          \
        if (t + 1 < NT) {                                                       \
            if (t + 2 < NT) { asm volatile("s_waitcnt vmcnt(8)" ::: "memory"); }\
            else            { asm volatile("s_waitcnt vmcnt(0)" ::: "memory"); }\
            __builtin_amdgcn_sched_barrier(0);                                  \
            __builtin_amdgcn_s_barrier();                                       \
        }                                                                       \
    }

// ---------------- 5. GEMM1: C = relu(A@Bt^T + bias + bias2), bf16 ----------
__global__ __launch_bounds__(256, 2) void gemm_relu(const unsigned short* __restrict__ A,
                                                    const unsigned short* __restrict__ Bt,
                                                    const float* __restrict__ bias,
                                                    const float* __restrict__ bias2,
                                                    unsigned short* __restrict__ C,
                                                    int M, int N, int K, int NBN) {
    __shared__ __align__(16) unsigned short As[2][128 * 64];
    __shared__ __align__(16) unsigned short Bs[2][128 * 64];
    const int blk = blockIdx.x, xcd = blk & 7, j = blk >> 3;
    const int bm = xcd * 16 + j / NBN, bn = j % NBN;

    GEMM_CORE_LOOP

#pragma unroll
    for (int m = 0; m < 4; ++m) {
        const int grow_base = bm * 128 + wr * 64 + m * 16 + l4 * 4;
#pragma unroll
        for (int n = 0; n < 4; ++n) {
            const int gcol = bn * 128 + wc * 64 + n * 16 + l15;
            const float bv = bias[gcol] + bias2[gcol];
#pragma unroll
            for (int j2 = 0; j2 < 4; ++j2) {
                float v = fmaxf(acc[m][n][j2] + bv, 0.f);
                C[(long long)(grow_base + j2) * N + gcol] = f2bf(v);
            }
        }
    }
}

// ---------------- 5b. GEMM2 with fused W3-dot epilogue ---------------------
__global__ __launch_bounds__(256, 2) void gemm2_fused(const unsigned short* __restrict__ A,
                                                      const unsigned short* __restrict__ Bt,
                                                      const float* __restrict__ bias,
                                                      const float* __restrict__ W3,
                                                      float* __restrict__ logits,
                                                      int M, int N, int K, int NBN) {
    __shared__ __align__(16) unsigned short As[2][128 * 64];
    __shared__ __align__(16) unsigned short Bs[2][128 * 64];
    const int blk = blockIdx.x, xcd = blk & 7, j = blk >> 3;
    const int bm = xcd * 16 + j / NBN, bn = j % NBN;

    GEMM_CORE_LOOP

#pragma unroll
    for (int m = 0; m < 4; ++m) {
        float part[4] = {0.f, 0.f, 0.f, 0.f};
#pragma unroll
        for (int n = 0; n < 4; ++n) {
            const int gcol = bn * 128 + wc * 64 + n * 16 + l15;
            const float bv = bias[gcol];
            const float w3 = W3[gcol];
#pragma unroll
            for (int j2 = 0; j2 < 4; ++j2) {
                float v = fmaxf(acc[m][n][j2] + bv, 0.f);
                part[j2] += v * w3;
            }
        }
#pragma unroll
        for (int off = 1; off < 16; off <<= 1)
#pragma unroll
            for (int j2 = 0; j2 < 4; ++j2) part[j2] += __shfl_xor(part[j2], off, 64);
        if (l15 == 0) {
            const int grow = bm * 128 + wr * 64 + m * 16 + l4 * 4;
#pragma unroll
            for (int j2 = 0; j2 < 4; ++j2) atomicAdd(&logits[grow + j2], part[j2]);
        }
    }
}

// ---------------- 6. sigmoid ------------------------------------------------
__global__ __launch_bounds__(256) void sigmoid_kernel(const float* __restrict__ logits,
                                                      const float* __restrict__ b3,
                                                      float* __restrict__ out) {
    const int i = blockIdx.x * 256 + threadIdx.x;
    out[i] = 1.0f / (1.0f + expf(-(logits[i] + b3[0])));
}

// ---------------- host ------------------------------------------------------
extern "C" void kernel_launch(void* const* d_in, const int* in_sizes, int n_in,
                              void* d_out, int out_size, void* d_ws, size_t ws_size,
                              hipStream_t stream) {
    const int*   idx = (const int*)d_in[0];
    const float* emb = (const float*)d_in[1];
    const float* W1  = (const float*)d_in[2];
    const float* b1  = (const float*)d_in[3];
    const float* W2  = (const float*)d_in[4];
    const float* b2  = (const float*)d_in[5];
    const float* W3  = (const float*)d_in[6];
    const float* b3  = (const float*)d_in[7];
    float* out = (float*)d_out;

    char* ws = (char*)d_ws;
    unsigned short* xb   = (unsigned short*)ws; ws += (size_t)BATCH * DW * 2;   // 32MB
    unsigned short* h1   = (unsigned short*)ws; ws += (size_t)BATCH * DW * 2;   // 32MB
    unsigned short* w1t  = (unsigned short*)ws; ws += (size_t)1024 * 1024 * 2;  // 2MB
    unsigned short* w2t  = (unsigned short*)ws; ws += (size_t)512 * 1024 * 2;   // 1MB
    float* ssum   = (float*)ws; ws += 4096;
    float* ssq    = (float*)ws; ws += 4096;
    float* b1n    = (float*)ws; ws += 4096;
    float* logits = (float*)ws; ws += (size_t)BATCH * 4;

    hipMemsetAsync(ssum, 0, 4096 * 3 + (size_t)BATCH * 4, stream);

    pool_kernel<<<(BATCH * NF * 4) / 256, 256, 0, stream>>>(idx, emb, xb);
    stats_kernel<<<BATCH / 128, 256, 0, stream>>>(xb, ssum, ssq);

    prep_weights<<<dim3(32, 32, 3), 256, 0, stream>>>(W1, W2, ssum, ssq, w1t, w2t, b1n);

    gemm_relu<<<(BATCH / 128) * (1024 / 128), 256, 0, stream>>>(
        xb, w1t, b1, b1n, h1, BATCH, 1024, 1024, 1024 / 128);
    gemm2_fused<<<(BATCH / 128) * (512 / 128), 256, 0, stream>>>(
        h1, w2t, b2, W3, logits, BATCH, 512, 1024, 512 / 128);

    sigmoid_kernel<<<BATCH / 256, 256, 0, stream>>>(logits, b3, out);
}

// Round 11
// 295.809 us; speedup vs baseline: 1.6054x; 1.0031x over previous
//
#include <hip/hip_runtime.h>
#include <hip/hip_bf16.h>
#include <math.h>

typedef __attribute__((ext_vector_type(8))) short  short8;
typedef __attribute__((ext_vector_type(4))) float  f32x4;
typedef __attribute__((ext_vector_type(4))) unsigned short u16x4;
typedef __attribute__((ext_vector_type(8))) unsigned short u16x8;
typedef int i32x4 __attribute__((ext_vector_type(4), aligned(4)));
typedef int i32x2 __attribute__((ext_vector_type(2), aligned(4)));

#define BATCH 16384
#define NF    64
#define BAGL  10
#define ED    16
#define DW    1024   // F*E
#define VOCAB 1000000

static __device__ __forceinline__ unsigned short f2bf(float f) {
    unsigned int u = __builtin_bit_cast(unsigned int, f);
    unsigned int r = (u + 0x7fffu + ((u >> 16) & 1u)) >> 16;
    return (unsigned short)r;
}
static __device__ __forceinline__ float bf2f(unsigned short h) {
    unsigned int u = ((unsigned int)h) << 16;
    return __builtin_bit_cast(float, u);
}

// ---------------- 1. embedding gather + bag-sum (f32 table), bf16 x --------
// 4 threads/bag, 16B each. idx loads DEDUP'd across the 4-lane group
// (q0: idx[0..3] x4-load, q1: idx[4..7], q2: idx[8..9] x2-load) and shared
// via __shfl. VMEM insts/wave 20 -> 13: tests the TA/issue-bound hypothesis
// (line-count and per-wave-depth levers already falsified r2/r7/r8).
__global__ __launch_bounds__(256) void pool_kernel(const int* __restrict__ idx,
                                                   const float* __restrict__ emb,
                                                   unsigned short* __restrict__ xb) {
    const int gid = blockIdx.x * 256 + threadIdx.x;   // B*F*4 threads
    const int bag = gid >> 2;                         // b*F + f
    const int q   = gid & 3;                          // which float4 of E=16
    const int lb  = (threadIdx.x & 63) & ~3;          // 4-lane group base lane
    const int* ip = idx + (long long)bag * BAGL;

    i32x4 c4 = {0, 0, 0, 0};
    i32x2 c2 = {0, 0};
    if (q == 0)      c4 = *(const i32x4*)(ip);        // idx[0..3]
    else if (q == 1) c4 = *(const i32x4*)(ip + 4);    // idx[4..7]
    else if (q == 2) c2 = *(const i32x2*)(ip + 8);    // idx[8..9]

    int v[BAGL];
    v[0] = __shfl(c4.x, lb + 0); v[1] = __shfl(c4.y, lb + 0);
    v[2] = __shfl(c4.z, lb + 0); v[3] = __shfl(c4.w, lb + 0);
    v[4] = __shfl(c4.x, lb + 1); v[5] = __shfl(c4.y, lb + 1);
    v[6] = __shfl(c4.z, lb + 1); v[7] = __shfl(c4.w, lb + 1);
    v[8] = __shfl(c2.x, lb + 2); v[9] = __shfl(c2.y, lb + 2);

    f32x4 e[BAGL];
#pragma unroll
    for (int l = 0; l < BAGL; ++l)
        e[l] = *(const f32x4*)(emb + (((long long)v[l]) << 4) + (q << 2));

    f32x4 s01 = e[0] + e[1], s23 = e[2] + e[3], s45 = e[4] + e[5],
          s67 = e[6] + e[7], s89 = e[8] + e[9];
    f32x4 acc = ((s01 + s23) + (s45 + s67)) + s89;

    u16x4 o;
#pragma unroll
    for (int j = 0; j < 4; ++j) o[j] = f2bf(acc[j]);
    *(u16x4*)(xb + (((long long)bag) << 4) + (q << 2)) = o;
}

// ---------------- 2. per-column sum / sumsq over batch ---------------------
// 128 blocks x 128-row register accumulation -> 262K atomics (~2K per 64B
// line). r9 lesson: atomic count scales with block count; keep blocks low.
__global__ __launch_bounds__(256) void stats_kernel(const unsigned short* __restrict__ xb,
                                                    float* __restrict__ ssum,
                                                    float* __restrict__ ssq) {
    const int t = threadIdx.x;                 // cols 4t..4t+3
    const long long r0 = (long long)blockIdx.x * 128;
    float s[4] = {0, 0, 0, 0}, q[4] = {0, 0, 0, 0};
    for (int r = 0; r < 128; ++r) {
        const u16x4 v = *(const u16x4*)(xb + (r0 + r) * DW + t * 4);
#pragma unroll
        for (int j = 0; j < 4; ++j) { float f = bf2f(v[j]); s[j] += f; q[j] += f * f; }
    }
#pragma unroll
    for (int j = 0; j < 4; ++j) {
        atomicAdd(&ssum[t * 4 + j], s[j]);
        atomicAdd(&ssq [t * 4 + j], q[j]);
    }
}

static __device__ __forceinline__ float rsig_of(const float* ssum, const float* ssq, int c) {
    const float m = ssum[c] * (1.0f / (float)BATCH);
    const float v = ssq[c] * (1.0f / (float)BATCH) - m * m;
    return rsqrtf(v + 1e-5f);
}

// ---------------- 3. weight prep, one launch -------------------------------
// z=0: w1t[c][r] = W1[r][c]*rsig[r]; z=1: w2t[c][r] = W2[r][c];
// z=2 (bx<4, by<8): b1n[n] -= sum_k mu[k]*rsig[k]*W1[k,n]
__global__ __launch_bounds__(256) void prep_weights(const float* __restrict__ W1,
                                                    const float* __restrict__ W2,
                                                    const float* __restrict__ ssum,
                                                    const float* __restrict__ ssq,
                                                    unsigned short* __restrict__ w1t,
                                                    unsigned short* __restrict__ w2t,
                                                    float* __restrict__ b1n) {
    const int z = blockIdx.z;
    const int bx = blockIdx.x, by = blockIdx.y;
    if (z == 2) {
        if (bx >= 4 || by >= 8) return;
        __shared__ float mu_s[128];
        const int n = bx * 256 + threadIdx.x;
        const int k0 = by * 128;
        if (threadIdx.x < 128) {
            const int k = k0 + threadIdx.x;
            mu_s[threadIdx.x] = ssum[k] * (1.0f / (float)BATCH) * rsig_of(ssum, ssq, k);
        }
        __syncthreads();
        float acc = 0.f;
#pragma unroll 4
        for (int k = 0; k < 128; ++k)
            acc += mu_s[k] * W1[(long long)(k0 + k) * 1024 + n];
        atomicAdd(&b1n[n], -acc);
        return;
    }
    if (z == 1 && bx >= 16) return;
    __shared__ float tile[32][33];
    const int tx = threadIdx.x & 31, ty = threadIdx.x >> 5;
    const float* src = z ? W2 : W1;
    unsigned short* dst = z ? w2t : w1t;
    const int C = z ? 512 : 1024;
#pragma unroll
    for (int i = 0; i < 4; ++i) {
        const int r = by * 32 + ty + i * 8, c = bx * 32 + tx;
        float v = src[(long long)r * C + c];
        if (!z) v *= rsig_of(ssum, ssq, r);
        tile[ty + i * 8][tx] = v;
    }
    __syncthreads();
#pragma unroll
    for (int i = 0; i < 4; ++i) {
        const int oc = bx * 32 + ty + i * 8;
        dst[(long long)oc * 1024 + by * 32 + tx] = f2bf(tile[tx][ty + i * 8]);
    }
}

// ============ pipelined 128x128 bf16 GEMM core (proven r5 structure) =======
#define GEMM_STAGE(dstA, dstB, kt)                                              \
  {                                                                             \
    const int k0s = (kt) * 64;                                                  \
    _Pragma("unroll")                                                           \
    for (int g = 0; g < 4; ++g) {                                               \
      const int cid = g * 256 + tid;                                            \
      const int rr = cid >> 3, pos = cid & 7;                                   \
      const int csrc = (pos ^ (rr & 7)) << 3;                                   \
      __builtin_amdgcn_global_load_lds(                                         \
        (const __attribute__((address_space(1))) void*)(A + a_base + (long long)rr * K + k0s + csrc), \
        (__attribute__((address_space(3))) void*)(&(dstA)[cid * 8]), 16, 0, 0); \
      __builtin_amdgcn_global_load_lds(                                         \
        (const __attribute__((address_space(1))) void*)(Bt + b_base + (long long)rr * K + k0s + csrc), \
        (__attribute__((address_space(3))) void*)(&(dstB)[cid * 8]), 16, 0, 0); \
    }                                                                           \
  }

#define GEMM_CORE_LOOP                                                          \
    const int tid = threadIdx.x;                                                \
    const int w = tid >> 6, l = tid & 63;                                       \
    const int wr = w >> 1, wc = w & 1;                                          \
    const int l15 = l & 15, l4 = l >> 4;                                        \
    f32x4 acc[4][4] = {};                                                       \
    const long long a_base = (long long)bm * 128 * K;                           \
    const long long b_base = (long long)bn * 128 * K;                           \
    const int NT = K >> 6;                                                      \
    GEMM_STAGE(As[0], Bs[0], 0)                                                 \
    GEMM_STAGE(As[1], Bs[1], 1)                                                 \
    asm volatile("s_waitcnt vmcnt(8)" ::: "memory");                            \
    __builtin_amdgcn_sched_barrier(0);                                          \
    __builtin_amdgcn_s_barrier();                                               \
    for (int t = 0; t < NT; ++t) {                                              \
        const unsigned short* Ap = As[t & 1];                                   \
        const unsigned short* Bp = Bs[t & 1];                                   \
        short8 a[2][4], b[2][4];                                                \
        _Pragma("unroll")                                                       \
        for (int kk = 0; kk < 2; ++kk) {                                        \
            const int swz = ((kk * 4 + l4) ^ (l15 & 7)) << 3;                   \
            _Pragma("unroll")                                                   \
            for (int m = 0; m < 4; ++m)                                         \
                a[kk][m] = *(const short8*)(Ap + (wr * 64 + m * 16 + l15) * 64 + swz); \
            _Pragma("unroll")                                                   \
            for (int n = 0; n < 4; ++n)                                         \
                b[kk][n] = *(const short8*)(Bp + (wc * 64 + n * 16 + l15) * 64 + swz); \
        }                                                                       \
        asm volatile("s_waitcnt lgkmcnt(0)" ::: "memory");                      \
        __builtin_amdgcn_sched_barrier(0);                                      \
        __builtin_amdgcn_s_barrier();                                           \
        if (t + 2 < NT) { GEMM_STAGE(As[t & 1], Bs[t & 1], t + 2) }             \
        __builtin_amdgcn_s_setprio(1);                                          \
        _Pragma("unroll")                                                       \
        for (int kk = 0; kk < 2; ++kk)                                          \
            _Pragma("unroll")                                                   \
            for (int m = 0; m < 4; ++m)                                         \
                _Pragma("unroll")                                               \
                for (int n = 0; n < 4; ++n)                                     \
                    acc[m][n] = __builtin_amdgcn_mfma_f32_16x16x32_bf16(        \
                        a[kk][m], b[kk][n], acc[m][n], 0, 0, 0);                \
        __builtin_amdgcn_s_setprio(0);                                          \
        if (t + 1 < NT) {                                                       \
            if (t + 2 < NT) { asm volatile("s_waitcnt vmcnt(8)" ::: "memory"); }\
            else            { asm volatile("s_waitcnt vmcnt(0)" ::: "memory"); }\
            __builtin_amdgcn_sched_barrier(0);                                  \
            __builtin_amdgcn_s_barrier();                                       \
        }                                                                       \
    }

// ---------------- 5. GEMM1: C = relu(A@Bt^T + bias + bias2), bf16 ----------
__global__ __launch_bounds__(256, 2) void gemm_relu(const unsigned short* __restrict__ A,
                                                    const unsigned short* __restrict__ Bt,
                                                    const float* __restrict__ bias,
                                                    const float* __restrict__ bias2,
                                                    unsigned short* __restrict__ C,
                                                    int M, int N, int K, int NBN) {
    __shared__ __align__(16) unsigned short As[2][128 * 64];
    __shared__ __align__(16) unsigned short Bs[2][128 * 64];
    const int blk = blockIdx.x, xcd = blk & 7, j = blk >> 3;
    const int bm = xcd * 16 + j / NBN, bn = j % NBN;

    GEMM_CORE_LOOP

#pragma unroll
    for (int m = 0; m < 4; ++m) {
        const int grow_base = bm * 128 + wr * 64 + m * 16 + l4 * 4;
#pragma unroll
        for (int n = 0; n < 4; ++n) {
            const int gcol = bn * 128 + wc * 64 + n * 16 + l15;
            const float bv = bias[gcol] + bias2[gcol];
#pragma unroll
            for (int j2 = 0; j2 < 4; ++j2) {
                float v = fmaxf(acc[m][n][j2] + bv, 0.f);
                C[(long long)(grow_base + j2) * N + gcol] = f2bf(v);
            }
        }
    }
}

// ---------------- 5b. GEMM2 with fused W3-dot epilogue ---------------------
__global__ __launch_bounds__(256, 2) void gemm2_fused(const unsigned short* __restrict__ A,
                                                      const unsigned short* __restrict__ Bt,
                                                      const float* __restrict__ bias,
                                                      const float* __restrict__ W3,
                                                      float* __restrict__ logits,
                                                      int M, int N, int K, int NBN) {
    __shared__ __align__(16) unsigned short As[2][128 * 64];
    __shared__ __align__(16) unsigned short Bs[2][128 * 64];
    const int blk = blockIdx.x, xcd = blk & 7, j = blk >> 3;
    const int bm = xcd * 16 + j / NBN, bn = j % NBN;

    GEMM_CORE_LOOP

#pragma unroll
    for (int m = 0; m < 4; ++m) {
        float part[4] = {0.f, 0.f, 0.f, 0.f};
#pragma unroll
        for (int n = 0; n < 4; ++n) {
            const int gcol = bn * 128 + wc * 64 + n * 16 + l15;
            const float bv = bias[gcol];
            const float w3 = W3[gcol];
#pragma unroll
            for (int j2 = 0; j2 < 4; ++j2) {
                float v = fmaxf(acc[m][n][j2] + bv, 0.f);
                part[j2] += v * w3;
            }
        }
#pragma unroll
        for (int off = 1; off < 16; off <<= 1)
#pragma unroll
            for (int j2 = 0; j2 < 4; ++j2) part[j2] += __shfl_xor(part[j2], off, 64);
        if (l15 == 0) {
            const int grow = bm * 128 + wr * 64 + m * 16 + l4 * 4;
#pragma unroll
            for (int j2 = 0; j2 < 4; ++j2) atomicAdd(&logits[grow + j2], part[j2]);
        }
    }
}

// ---------------- 6. sigmoid ------------------------------------------------
__global__ __launch_bounds__(256) void sigmoid_kernel(const float* __restrict__ logits,
                                                      const float* __restrict__ b3,
                                                      float* __restrict__ out) {
    const int i = blockIdx.x * 256 + threadIdx.x;
    out[i] = 1.0f / (1.0f + expf(-(logits[i] + b3[0])));
}

// ---------------- host ------------------------------------------------------
extern "C" void kernel_launch(void* const* d_in, const int* in_sizes, int n_in,
                              void* d_out, int out_size, void* d_ws, size_t ws_size,
                              hipStream_t stream) {
    const int*   idx = (const int*)d_in[0];
    const float* emb = (const float*)d_in[1];
    const float* W1  = (const float*)d_in[2];
    const float* b1  = (const float*)d_in[3];
    const float* W2  = (const float*)d_in[4];
    const float* b2  = (const float*)d_in[5];
    const float* W3  = (const float*)d_in[6];
    const float* b3  = (const float*)d_in[7];
    float* out = (float*)d_out;

    char* ws = (char*)d_ws;
    unsigned short* xb   = (unsigned short*)ws; ws += (size_t)BATCH * DW * 2;   // 32MB
    unsigned short* h1   = (unsigned short*)ws; ws += (size_t)BATCH * DW * 2;   // 32MB
    unsigned short* w1t  = (unsigned short*)ws; ws += (size_t)1024 * 1024 * 2;  // 2MB
    unsigned short* w2t  = (unsigned short*)ws; ws += (size_t)512 * 1024 * 2;   // 1MB
    float* ssum   = (float*)ws; ws += 4096;
    float* ssq    = (float*)ws; ws += 4096;
    float* b1n    = (float*)ws; ws += 4096;
    float* logits = (float*)ws; ws += (size_t)BATCH * 4;

    hipMemsetAsync(ssum, 0, 4096 * 3 + (size_t)BATCH * 4, stream);

    pool_kernel<<<(BATCH * NF * 4) / 256, 256, 0, stream>>>(idx, emb, xb);
    stats_kernel<<<BATCH / 128, 256, 0, stream>>>(xb, ssum, ssq);

    prep_weights<<<dim3(32, 32, 3), 256, 0, stream>>>(W1, W2, ssum, ssq, w1t, w2t, b1n);

    gemm_relu<<<(BATCH / 128) * (1024 / 128), 256, 0, stream>>>(
        xb, w1t, b1, b1n, h1, BATCH, 1024, 1024, 1024 / 128);
    gemm2_fused<<<(BATCH / 128) * (512 / 128), 256, 0, stream>>>(
        h1, w2t, b2, W3, logits, BATCH, 512, 1024, 512 / 128);

    sigmoid_kernel<<<BATCH / 256, 256, 0, stream>>>(logits, b3, out);
}